// Round 1
// baseline (56.973 us; speedup 1.0000x reference)
//
#include <hip/hip_runtime.h>
#include <math.h>

#define IMG_W 512
#define IMG_H 512
#define RPT 8
#define STRIPS (IMG_H / RPT)   // 64 strips per column

// Load 3 horizontal taps (x-1, x, x+1) of row y, zero-padded at borders.
__device__ __forceinline__ void load3(const float* __restrict__ plane, int y, int x, float v[3]) {
    if ((unsigned)y >= (unsigned)IMG_H) { v[0] = v[1] = v[2] = 0.f; return; }
    const float* row = plane + (size_t)y * IMG_W;
    v[0] = (x > 0)         ? row[x - 1] : 0.f;
    v[1] = row[x];
    v[2] = (x < IMG_W - 1) ? row[x + 1] : 0.f;
}

__global__ __launch_bounds__(256) void loss_partial_kernel(
        const float* __restrict__ pred, const float* __restrict__ targ,
        float* __restrict__ partial) {
    const int tid   = blockIdx.x * 256 + threadIdx.x;
    const int x     = tid & (IMG_W - 1);
    const int rest  = tid >> 9;               // / IMG_W
    const int strip = rest & (STRIPS - 1);
    const int b     = rest >> 6;              // / STRIPS
    const float* p = pred + (size_t)b * IMG_H * IMG_W;
    const float* t = targ + (size_t)b * IMG_H * IMG_W;
    const int y0 = strip * RPT;

    const float eps2  = 0.001f * 0.001f;
    const float alpha = -10.0f;

    float pa[3], pb_[3], pc[3];
    float ta[3], tb_[3], tc[3];
    load3(p, y0 - 1, x, pa);
    load3(p, y0,     x, pb_);
    load3(t, y0 - 1, x, ta);
    load3(t, y0,     x, tb_);

    float sum = 0.f;
#pragma unroll
    for (int i = 0; i < RPT; ++i) {
        const int y = y0 + i;
        load3(p, y + 1, x, pc);
        load3(t, y + 1, x, tc);

        // Cross-correlation (conv2d semantics, no flip), zero padding.
        float sxp = (pa[2] + 2.f*pb_[2] + pc[2]) - (pa[0] + 2.f*pb_[0] + pc[0]);
        float syp = (pc[0] + 2.f*pc[1] + pc[2]) - (pa[0] + 2.f*pa[1] + pa[2]);
        float lpp = 9.f*pb_[1] - (pa[0]+pa[1]+pa[2] + pb_[0]+pb_[1]+pb_[2] + pc[0]+pc[1]+pc[2]);

        float sxt = (ta[2] + 2.f*tb_[2] + tc[2]) - (ta[0] + 2.f*tb_[0] + tc[0]);
        float syt = (tc[0] + 2.f*tc[1] + tc[2]) - (ta[0] + 2.f*ta[1] + ta[2]);
        float lpt = 9.f*tb_[1] - (ta[0]+ta[1]+ta[2] + tb_[0]+tb_[1]+tb_[2] + tc[0]+tc[1]+tc[2]);

        float ax = fabsf(sxp) * __expf(alpha * fabsf(sxt));
        float ay = fabsf(syp) * __expf(alpha * fabsf(syt));
        float al = fabsf(lpp) * __expf(alpha * fabsf(lpt));

        sum += 10.f * (sqrtf(ax*ax + eps2) + sqrtf(ay*ay + eps2)) + sqrtf(al*al + eps2);

#pragma unroll
        for (int j = 0; j < 3; ++j) {
            pa[j] = pb_[j]; pb_[j] = pc[j];
            ta[j] = tb_[j]; tb_[j] = tc[j];
        }
    }

    // wave (64-lane) reduce
#pragma unroll
    for (int off = 32; off > 0; off >>= 1) sum += __shfl_down(sum, off, 64);
    __shared__ float ws[4];
    const int lane = threadIdx.x & 63, wid = threadIdx.x >> 6;
    if (lane == 0) ws[wid] = sum;
    __syncthreads();
    if (threadIdx.x == 0) partial[blockIdx.x] = ws[0] + ws[1] + ws[2] + ws[3];
}

__global__ __launch_bounds__(256) void loss_final_kernel(
        const float* __restrict__ partial, int n, float* __restrict__ out, float scale) {
    float s = 0.f;
    for (int i = threadIdx.x; i < n; i += 256) s += partial[i];
#pragma unroll
    for (int off = 32; off > 0; off >>= 1) s += __shfl_down(s, off, 64);
    __shared__ float ws[4];
    const int lane = threadIdx.x & 63, wid = threadIdx.x >> 6;
    if (lane == 0) ws[wid] = s;
    __syncthreads();
    if (threadIdx.x == 0) out[0] = (ws[0] + ws[1] + ws[2] + ws[3]) * scale;
}

extern "C" void kernel_launch(void* const* d_in, const int* in_sizes, int n_in,
                              void* d_out, int out_size, void* d_ws, size_t ws_size,
                              hipStream_t stream) {
    const float* pred = (const float*)d_in[0];
    const float* targ = (const float*)d_in[1];
    float* out = (float*)d_out;
    float* partial = (float*)d_ws;

    const int total = in_sizes[0];                  // B*1*H*W = 16777216
    const int B = total / (IMG_H * IMG_W);          // 64
    const int nthreads = B * IMG_W * STRIPS;        // 2,097,152
    const int nblocks = nthreads / 256;             // 8192

    loss_partial_kernel<<<nblocks, 256, 0, stream>>>(pred, targ, partial);
    const float scale = 1.0f / (float)total;
    loss_final_kernel<<<1, 256, 0, stream>>>(partial, nblocks, out, scale);
}